// Round 5
// baseline (125.829 us; speedup 1.0000x reference)
//
#include <hip/hip_runtime.h>

// DWT db4, 6 levels, zero mode. x:[64, 262144] f32 ->
// concat(cA6, cD6, cD5, cD4, cD3, cD2, cD1) flat.
//
// R5: K1 = levels 1+2 REGISTER-FUSED, 2 phases only (stage -> sync -> compute).
// Tile = 256 cA2 outputs / 128 threads; each thread: 2 cA2 via 10 in-register
// cA1 from a 26-float x window (8x stride-1 b128 LDS reads of de-interleaved
// E/O). cD1 = one f4 nt store, cD2/cA2 = f2 stores. cA1 never touches LDS.
// K2 = levels 3-6 from ws (L3-resident), unchanged from R4.
//
// dwt: out[g] = sum_m RFILT[m]*src[2g-6+m], zeros outside [0,N).

#define NT1 128
#define NT2 256

#define N0 262144
#define M1 131075
#define M2 65541
#define M3 32774
#define M4 16390
#define M5 8198
#define M6 4102
#define WSTRIDE 65544  // ws row stride; 64*65544*4 = 16.0 MiB

#define OFF_A6 ((size_t)0)
#define OFF_D6 ((size_t)262528)
#define OFF_D5 ((size_t)525056)
#define OFF_D4 ((size_t)1049728)
#define OFF_D3 ((size_t)2098688)
#define OFF_D2 ((size_t)4196224)
#define OFF_D1 ((size_t)8390848)

typedef float f4_t __attribute__((ext_vector_type(4)));
typedef f4_t f4u_t __attribute__((aligned(4)));
typedef float f2_t __attribute__((ext_vector_type(2)));
typedef f2_t f2u_t __attribute__((aligned(4)));

__device__ __constant__ float RLO[8] = {
    0.23037781330885523f, 0.7148465705525415f, 0.6308807679295904f,
    -0.02798376941698385f, -0.18703481171888114f, 0.030841381835986965f,
    0.032883011666982945f, -0.010597401784997278f};
__device__ __constant__ float RHI[8] = {
    -0.010597401784997278f, -0.032883011666982945f, 0.030841381835986965f,
    0.18703481171888114f, -0.02798376941698385f, -0.6308807679295904f,
    0.7148465705525415f, -0.23037781330885523f};

// ============================ K1: levels 1+2 (fused) ============================
// tile q (0..256): cA2/cD2 own [256q, 256q+256); cD1 own [512q, 512q+512).
// Thread c (0..127): cA2 at 256q+2c+{0,1} <- cA1[H..H+9], H = 512q+4c-6,
// <- x[2H-6 .. 2H+19] (26 floats). Staged x_loc base sb = 1024q-20 (0 mod 4):
// window = x_loc[8c+2 .. 8c+27] -> E[4c+1..4c+13], O[4c+1..4c+13].
// LDS: fast: E [0,528) O [528,1056); edge: xf [0,1044) a1 [1056,1578).
__global__ __launch_bounds__(NT1, 6) void dwt_k1(const float* __restrict__ x,
                                                 float* __restrict__ out,
                                                 float* __restrict__ ws) {
  const int q = blockIdx.x;
  const int row = blockIdx.y;
  const int tid = threadIdx.x;
  __shared__ __align__(16) float lds[1600];

  const int sb = (q << 10) - 20;
  float* __restrict__ gD1 = out + OFF_D1 + (size_t)row * M1;
  float* __restrict__ gD2 = out + OFF_D2 + (size_t)row * M2;
  float* __restrict__ gA2 = ws + (size_t)row * WSTRIDE;

  if (q >= 1 && q <= 255) {
    // ---- fast path ----
    const f4_t* __restrict__ xs4 = (const f4_t*)(x + (size_t)row * N0 + sb);
    float2* E2 = (float2*)(lds);
    float2* O2 = (float2*)(lds + 528);
    for (int m = tid; m < 261; m += NT1) {
      f4_t v = xs4[m];
      E2[m] = make_float2(v.x, v.z);
      O2[m] = make_float2(v.y, v.w);
    }
    __syncthreads();

    const int c = tid;  // 128 chunks == 128 threads
    const f4_t* E4 = (const f4_t*)(lds);
    const f4_t* O4 = (const f4_t*)(lds + 528);
    f4_t ea = E4[c], eb = E4[c + 1], ec = E4[c + 2], ed = E4[c + 3];
    f4_t oa = O4[c], ob = O4[c + 1], oc = O4[c + 2], od = O4[c + 3];
    float e[13] = {ea.y, ea.z, ea.w, eb.x, eb.y, eb.z, eb.w,
                   ec.x, ec.y, ec.z, ec.w, ed.x, ed.y};
    float o[13] = {oa.y, oa.z, oa.w, ob.x, ob.y, ob.z, ob.w,
                   oc.x, oc.y, oc.z, oc.w, od.x, od.y};

    float A1[10];
#pragma unroll
    for (int i = 0; i < 10; ++i) {
      float aa = 0.f;
#pragma unroll
      for (int t = 0; t < 4; ++t) {
        aa = fmaf(RLO[2 * t], e[i + t], aa);
        aa = fmaf(RLO[2 * t + 1], o[i + t], aa);
      }
      A1[i] = aa;
    }
    f4_t d1v;
#pragma unroll
    for (int j = 0; j < 4; ++j) {  // cD1 at h = 512q+4c+j  (i = j+6)
      float dd = 0.f;
#pragma unroll
      for (int t = 0; t < 4; ++t) {
        dd = fmaf(RHI[2 * t], e[j + 6 + t], dd);
        dd = fmaf(RHI[2 * t + 1], o[j + 6 + t], dd);
      }
      d1v[j] = dd;
    }
    __builtin_nontemporal_store(d1v, (f4u_t*)(gD1 + ((q << 9) + 4 * c)));

    f2_t a2v, d2v;
#pragma unroll
    for (int j = 0; j < 2; ++j) {
      float aa = 0.f, dd = 0.f;
#pragma unroll
      for (int m = 0; m < 8; ++m) {
        aa = fmaf(RLO[m], A1[2 * j + m], aa);
        dd = fmaf(RHI[m], A1[2 * j + m], dd);
      }
      a2v[j] = aa;
      d2v[j] = dd;
    }
    const int g2 = (q << 8) + 2 * c;
    __builtin_nontemporal_store(d2v, (f2u_t*)(gD2 + g2));
    *(f2_t*)(gA2 + g2) = a2v;  // cached: K2 reads it
  } else {
    // ---- edge path: q == 0 or q == 256 ----
    float* xf = lds;          // 1044
    float* a1 = lds + 1056;   // 522 (use [0,518))
    const float* __restrict__ xr = x + (size_t)row * N0;
    for (int l = tid; l < 1044; l += NT1) {
      int g = sb + l;
      xf[l] = (g >= 0 && g < N0) ? xr[g] : 0.f;
    }
    __syncthreads();
    const int b1e = (q << 9) - 6;
    for (int l = tid; l < 518; l += NT1) {
      float aa = 0.f, dd = 0.f;
#pragma unroll
      for (int m = 0; m < 8; ++m) {
        float v = xf[2 * l + 2 + m];
        aa = fmaf(RLO[m], v, aa);
        dd = fmaf(RHI[m], v, dd);
      }
      a1[l] = aa;
      int h = b1e + l;
      if (l >= 6 && h < M1) __builtin_nontemporal_store(dd, gD1 + h);
    }
    __syncthreads();
    for (int l2 = tid; l2 < 256; l2 += NT1) {
      int g2 = (q << 8) + l2;
      if (g2 < M2) {
        float aa = 0.f, dd = 0.f;
#pragma unroll
        for (int m = 0; m < 8; ++m) {
          float v = a1[2 * l2 + m];
          aa = fmaf(RLO[m], v, aa);
          dd = fmaf(RHI[m], v, dd);
        }
        __builtin_nontemporal_store(dd, gD2 + g2);
        gA2[g2] = aa;
      }
    }
  }
}

// ============================ K2: levels 3-6 (as R4) ============================
template <int NC, int SLO, int SHI, int SHIFT, bool A_GLOBAL, bool A_NT>
__device__ __forceinline__ void level_fast(const f4_t* __restrict__ sE4,
                                           const f4_t* __restrict__ sO4,
                                           float2* __restrict__ dE2,
                                           float2* __restrict__ dO2,
                                           float* __restrict__ gA,
                                           float* __restrict__ gD) {
  for (int c = threadIdx.x; c < NC; c += NT2) {
    f4_t e0 = sE4[c], e1 = sE4[c + 1];
    f4_t o0 = sO4[c], o1 = sO4[c + 1];
    float e[8] = {e0.x, e0.y, e0.z, e0.w, e1.x, e1.y, e1.z, e1.w};
    float o[8] = {o0.x, o0.y, o0.z, o0.w, o1.x, o1.y, o1.z, o1.w};
    float a[4], d[4];
#pragma unroll
    for (int j = 0; j < 4; ++j) {
      float aa = 0.f, dd = 0.f;
#pragma unroll
      for (int t = 0; t < 4; ++t) {
        float ev = e[j + t + SHIFT], ov = o[j + t + SHIFT];
        aa = fmaf(RLO[2 * t], ev, aa);
        aa = fmaf(RLO[2 * t + 1], ov, aa);
        dd = fmaf(RHI[2 * t], ev, dd);
        dd = fmaf(RHI[2 * t + 1], ov, dd);
      }
      a[j] = aa;
      d[j] = dd;
    }
    if (A_GLOBAL) {
      f4_t av = {a[0], a[1], a[2], a[3]};
      if (A_NT)
        __builtin_nontemporal_store(av, (f4u_t*)(gA + 4 * c));
      else
        *(f4u_t*)(gA + 4 * c) = av;
    } else {
      dE2[c] = make_float2(a[0], a[2]);
      dO2[c] = make_float2(a[1], a[3]);
    }
    const int l0 = 4 * c;
    const int lo = l0 < SLO ? SLO : l0;
    const int hi = (l0 + 4) < SHI ? (l0 + 4) : SHI;
    if (lo == l0 && hi == l0 + 4) {
      f4_t dv = {d[0], d[1], d[2], d[3]};
      __builtin_nontemporal_store(dv, (f4u_t*)(gD + l0));
    } else {
      for (int j = lo - l0; j < hi - l0; ++j)
        __builtin_nontemporal_store(d[j], gD + l0 + j);
    }
  }
}

__global__ __launch_bounds__(NT2, 8) void dwt_k2(const float* __restrict__ ws,
                                                 float* __restrict__ out) {
  const int p = blockIdx.x;
  const int row = blockIdx.y;
  const int tid = threadIdx.x;
  __shared__ __align__(16) float lds[1680];

  const int b6 = p << 6;
  const int b5 = (p << 7) - 6;
  const int b4 = (p << 8) - 18;
  const int b3 = (p << 9) - 42;
  const int b2t = (p << 10) - 90;

  float* gD3 = out + OFF_D3 + (size_t)row * M3 + b3;
  float* gD4 = out + OFF_D4 + (size_t)row * M4 + b4;
  float* gD5 = out + OFF_D5 + (size_t)row * M5 + b5;
  float* gD6 = out + OFF_D6 + (size_t)row * M6 + b6;
  float* gA6 = out + OFF_A6 + (size_t)row * M6 + b6;
  const float* __restrict__ wr = ws + (size_t)row * WSTRIDE;

  if (p >= 1 && p <= 63) {
    const f4_t* __restrict__ s4 = (const f4_t*)(wr + (b2t - 2));
    float2* Ep2 = (float2*)(lds + 0);
    float2* Op2 = (float2*)(lds + 560);
    for (int m = tid; m < 279; m += NT2) {
      f4_t v = s4[m];
      Ep2[m] = make_float2(v.x, v.z);
      Op2[m] = make_float2(v.y, v.w);
    }
    __syncthreads();
    level_fast<139, 0, 554, 1, false, false>(
        (const f4_t*)(lds + 0), (const f4_t*)(lds + 560),
        (float2*)(lds + 1120), (float2*)(lds + 1400), nullptr, gD3);
    __syncthreads();
    level_fast<69, 0, 274, 0, false, false>(
        (const f4_t*)(lds + 1120), (const f4_t*)(lds + 1400),
        (float2*)(lds + 0), (float2*)(lds + 560), nullptr, gD4);
    __syncthreads();
    level_fast<34, 0, 134, 0, false, false>(
        (const f4_t*)(lds + 0), (const f4_t*)(lds + 560),
        (float2*)(lds + 1120), (float2*)(lds + 1400), nullptr, gD5);
    __syncthreads();
    level_fast<16, 0, 64, 0, true, true>(
        (const f4_t*)(lds + 1120), (const f4_t*)(lds + 1400), nullptr, nullptr,
        gA6, gD6);
  } else {
    float* xf = lds;
    float* bb = lds + 1120;
    for (int l = tid; l < 1116; l += NT2) {
      int g = b2t + l;
      xf[l] = (g >= 0 && g < M2) ? wr[g] : 0.f;
    }
    __syncthreads();
    for (int l = tid; l < 554; l += NT2) {
      int g = b3 + l;
      float aa = 0.f, dd = 0.f;
      if (g >= 0 && g < M3) {
#pragma unroll
        for (int m = 0; m < 8; ++m) {
          float v = xf[2 * l + m];
          aa = fmaf(RLO[m], v, aa);
          dd = fmaf(RHI[m], v, dd);
        }
      }
      bb[l] = aa;
      if (l >= 42 && g < M3) __builtin_nontemporal_store(dd, gD3 + l);
    }
    __syncthreads();
    for (int l = tid; l < 274; l += NT2) {
      int g = b4 + l;
      float aa = 0.f, dd = 0.f;
      if (g >= 0 && g < M4) {
#pragma unroll
        for (int m = 0; m < 8; ++m) {
          float v = bb[2 * l + m];
          aa = fmaf(RLO[m], v, aa);
          dd = fmaf(RHI[m], v, dd);
        }
      }
      lds[l] = aa;
      if (l >= 18 && g < M4) __builtin_nontemporal_store(dd, gD4 + l);
    }
    __syncthreads();
    for (int l = tid; l < 134; l += NT2) {
      int g = b5 + l;
      float aa = 0.f, dd = 0.f;
      if (g >= 0 && g < M5) {
#pragma unroll
        for (int m = 0; m < 8; ++m) {
          float v = lds[2 * l + m];
          aa = fmaf(RLO[m], v, aa);
          dd = fmaf(RHI[m], v, dd);
        }
      }
      bb[l] = aa;
      if (l >= 6 && g < M5) __builtin_nontemporal_store(dd, gD5 + l);
    }
    __syncthreads();
    for (int l = tid; l < 64; l += NT2) {
      int g = b6 + l;
      if (g < M6) {
        float aa = 0.f, dd = 0.f;
#pragma unroll
        for (int m = 0; m < 8; ++m) {
          float v = bb[2 * l + m];
          aa = fmaf(RLO[m], v, aa);
          dd = fmaf(RHI[m], v, dd);
        }
        __builtin_nontemporal_store(aa, gA6 + l);
        __builtin_nontemporal_store(dd, gD6 + l);
      }
    }
  }
}

extern "C" void kernel_launch(void* const* d_in, const int* in_sizes, int n_in,
                              void* d_out, int out_size, void* d_ws,
                              size_t ws_size, hipStream_t stream) {
  const float* x = (const float*)d_in[0];
  float* out = (float*)d_out;
  float* ws = (float*)d_ws;
  dwt_k1<<<dim3(257, 64), NT1, 0, stream>>>(x, out, ws);
  dwt_k2<<<dim3(65, 64), NT2, 0, stream>>>(ws, out);
}

// Round 6
// 123.098 us; speedup vs baseline: 1.0222x; 1.0222x over previous
//
#include <hip/hip_runtime.h>

// DWT db4, 6 levels, zero mode. x:[64, 262144] f32 ->
// concat(cA6, cD6, cD5, cD4, cD3, cD2, cD1) flat.
//
// R6: ONE kernel, role-split grid, zero workspace traffic.
//  Role A (blockIdx.x in [0,257)): levels 1+2 register-fused (R5-K1 proven
//    structure), writes cD1 + cD2 (75% of output bytes). 2 phases.
//  Role B (blockIdx.x in [257,386)): levels 3-6, recomputing lvl1+2 from x.
//    Pair-register-fused: P1 lvl1+2 -> cA2(LDS); P2 lvl3+4 -> cD3,cD4 +
//    cA4(LDS); P3 lvl5+6 -> cD5, cD6, cA6. 4 phases.
//  Edge tiles share the fast path: zero-padded cascade is SELF-CONSISTENT
//  (cA_k outside [0,M_k) computes to exactly 0 from zero-padded inputs,
//  since 2*M_k-6 >= M_{k-1} at every level), so zero-filled staging +
//  store guards are sufficient.
//
// dwt: out[g] = sum_m RFILT[m]*src[2g-6+m], zeros outside [0,N).
// De-interleaved E[k]=src[2k], O[k]=src[2k+1]:
//   out_l = sum_t RLO[2t]*E[.] + RLO[2t+1]*O[.]

#define NT 128

#define N0 262144
#define M1 131075
#define M2 65541
#define M3 32774
#define M4 16390
#define M5 8198
#define M6 4102

#define OFF_A6 ((size_t)0)
#define OFF_D6 ((size_t)262528)
#define OFF_D5 ((size_t)525056)
#define OFF_D4 ((size_t)1049728)
#define OFF_D3 ((size_t)2098688)
#define OFF_D2 ((size_t)4196224)
#define OFF_D1 ((size_t)8390848)

typedef float f4_t __attribute__((ext_vector_type(4)));
typedef f4_t f4u_t __attribute__((aligned(4)));
typedef float f2_t __attribute__((ext_vector_type(2)));
typedef f2_t f2u_t __attribute__((aligned(4)));

__device__ __constant__ float RLO[8] = {
    0.23037781330885523f, 0.7148465705525415f, 0.6308807679295904f,
    -0.02798376941698385f, -0.18703481171888114f, 0.030841381835986965f,
    0.032883011666982945f, -0.010597401784997278f};
__device__ __constant__ float RHI[8] = {
    -0.010597401784997278f, -0.032883011666982945f, 0.030841381835986965f,
    0.18703481171888114f, -0.02798376941698385f, -0.6308807679295904f,
    0.7148465705525415f, -0.23037781330885523f};

// LDS float layout (shared by both roles), 3192 floats = 12768 B:
//  role A: aE [0,536)  aO [536,1072)
//  role B: xE [0,1216) xO [1216,2432) c2E [2432,2736) c2O [2736,3040)
//          c4E [3040,3116) c4O [3116,3192)

__global__ __launch_bounds__(NT, 6) void dwt_all(const float* __restrict__ x,
                                                 float* __restrict__ out) {
  const int bx = blockIdx.x;
  const int row = blockIdx.y;
  const int tid = threadIdx.x;
  __shared__ __align__(16) float lds[3192];
  const float* __restrict__ xr = x + (size_t)row * N0;

  if (bx < 257) {
    // ======================= ROLE A: levels 1+2 =======================
    // tile q: cD1 own [512q, 512q+512) (guarded), cD2 own [256q, +256).
    const int q = bx;
    const int sb = (q << 10) - 20;  // x stage base, == 0 mod 4
    float2* E2 = (float2*)(lds);
    float2* O2 = (float2*)(lds + 536);
    for (int m = tid; m < 264; m += NT) {
      int g = sb + 4 * m;
      f4_t v = {0.f, 0.f, 0.f, 0.f};
      if (g >= 0 && g <= N0 - 4) v = *(const f4_t*)(xr + g);
      E2[m] = make_float2(v.x, v.z);
      O2[m] = make_float2(v.y, v.w);
    }
    __syncthreads();

    const int c = tid;
    const f4_t* E4 = (const f4_t*)(lds);
    const f4_t* O4 = (const f4_t*)(lds + 536);
    f4_t ea = E4[c], eb = E4[c + 1], ec = E4[c + 2], ed = E4[c + 3];
    f4_t oa = O4[c], ob = O4[c + 1], oc = O4[c + 2], od = O4[c + 3];
    float e[13] = {ea.y, ea.z, ea.w, eb.x, eb.y, eb.z, eb.w,
                   ec.x, ec.y, ec.z, ec.w, ed.x, ed.y};
    float o[13] = {oa.y, oa.z, oa.w, ob.x, ob.y, ob.z, ob.w,
                   oc.x, oc.y, oc.z, oc.w, od.x, od.y};

    float A1[10];
#pragma unroll
    for (int i = 0; i < 10; ++i) {
      float aa = 0.f;
#pragma unroll
      for (int t = 0; t < 4; ++t) {
        aa = fmaf(RLO[2 * t], e[i + t], aa);
        aa = fmaf(RLO[2 * t + 1], o[i + t], aa);
      }
      A1[i] = aa;
    }
    f4_t d1v;
#pragma unroll
    for (int j = 0; j < 4; ++j) {
      float dd = 0.f;
#pragma unroll
      for (int t = 0; t < 4; ++t) {
        dd = fmaf(RHI[2 * t], e[j + 6 + t], dd);
        dd = fmaf(RHI[2 * t + 1], o[j + 6 + t], dd);
      }
      d1v[j] = dd;
    }
    float* __restrict__ gD1 = out + OFF_D1 + (size_t)row * M1;
    const int h0 = (q << 9) + 4 * c;
    if (h0 + 4 <= M1) {
      __builtin_nontemporal_store(d1v, (f4u_t*)(gD1 + h0));
    } else {
#pragma unroll
      for (int j = 0; j < 4; ++j)
        if (h0 + j < M1) __builtin_nontemporal_store(d1v[j], gD1 + h0 + j);
    }

    f2_t d2v;
#pragma unroll
    for (int j = 0; j < 2; ++j) {
      float dd = 0.f;
#pragma unroll
      for (int m = 0; m < 8; ++m) dd = fmaf(RHI[m], A1[2 * j + m], dd);
      d2v[j] = dd;
    }
    float* __restrict__ gD2 = out + OFF_D2 + (size_t)row * M2;
    const int g0 = (q << 8) + 2 * c;
    if (g0 + 2 <= M2) {
      __builtin_nontemporal_store(d2v, (f2u_t*)(gD2 + g0));
    } else if (g0 < M2) {
      __builtin_nontemporal_store(d2v[0], gD2 + g0);
    }
  } else {
    // ======================= ROLE B: levels 3-6 =======================
    // tile p: own cD3 [256p,+256) cD4 [128p,+128) cD5 [64p,+64)
    //         cD6/cA6 [32p,+32) — all store-guarded vs M_k.
    const int p = bx - 257;
    const int sb = (p << 11) - 380;  // x stage base, == 0 mod 4
    float2* xE2 = (float2*)(lds);
    float2* xO2 = (float2*)(lds + 1216);
    for (int m = tid; m < 607; m += NT) {
      int g = sb + 4 * m;
      f4_t v = {0.f, 0.f, 0.f, 0.f};
      if (g >= 0 && g <= N0 - 4) v = *(const f4_t*)(xr + g);
      xE2[m] = make_float2(v.x, v.z);
      xO2[m] = make_float2(v.y, v.w);
    }
    __syncthreads();

    // ---- P1: lvl1+2 -> cA2 pairs into LDS (301 pairs, window base b2=512p-90)
    {
      const f4_t* E4 = (const f4_t*)(lds);
      const f4_t* O4 = (const f4_t*)(lds + 1216);
      float* c2E = lds + 2432;
      float* c2O = lds + 2736;
      for (int j = tid; j < 301; j += NT) {
        f4_t ea = E4[j], eb = E4[j + 1], ec = E4[j + 2], ed = E4[j + 3];
        f4_t oa = O4[j], ob = O4[j + 1], oc = O4[j + 2], od = O4[j + 3];
        float e[13] = {ea.y, ea.z, ea.w, eb.x, eb.y, eb.z, eb.w,
                       ec.x, ec.y, ec.z, ec.w, ed.x, ed.y};
        float o[13] = {oa.y, oa.z, oa.w, ob.x, ob.y, ob.z, ob.w,
                       oc.x, oc.y, oc.z, oc.w, od.x, od.y};
        float A1[10];
#pragma unroll
        for (int i = 0; i < 10; ++i) {
          float aa = 0.f;
#pragma unroll
          for (int t = 0; t < 4; ++t) {
            aa = fmaf(RLO[2 * t], e[i + t], aa);
            aa = fmaf(RLO[2 * t + 1], o[i + t], aa);
          }
          A1[i] = aa;
        }
        float a2e = 0.f, a2o = 0.f;
#pragma unroll
        for (int m = 0; m < 8; ++m) {
          a2e = fmaf(RLO[m], A1[m], a2e);
          a2o = fmaf(RLO[m], A1[m + 2], a2o);
        }
        c2E[j] = a2e;
        c2O[j] = a2o;
      }
    }
    __syncthreads();

    // ---- P2: lvl3+4 -> cD3, cD4, cA4 pairs into LDS (73 pairs, b4=128p-18)
    if (tid < 73) {
      const int j = tid;
      const f4_t* E4 = (const f4_t*)(lds + 2432);
      const f4_t* O4 = (const f4_t*)(lds + 2736);
      f4_t ea = E4[j], eb = E4[j + 1], ec = E4[j + 2], ed = E4[j + 3];
      f4_t oa = O4[j], ob = O4[j + 1], oc = O4[j + 2], od = O4[j + 3];
      float e[13] = {ea.x, ea.y, ea.z, ea.w, eb.x, eb.y, eb.z,
                     eb.w, ec.x, ec.y, ec.z, ec.w, ed.x};
      float o[13] = {oa.x, oa.y, oa.z, oa.w, ob.x, ob.y, ob.z,
                     ob.w, oc.x, oc.y, oc.z, oc.w, od.x};
      float A3[10];
#pragma unroll
      for (int i = 0; i < 10; ++i) {
        float aa = 0.f;
#pragma unroll
        for (int t = 0; t < 4; ++t) {
          aa = fmaf(RLO[2 * t], e[i + t], aa);
          aa = fmaf(RLO[2 * t + 1], o[i + t], aa);
        }
        A3[i] = aa;
      }
      float a4e = 0.f, a4o = 0.f;
#pragma unroll
      for (int m = 0; m < 8; ++m) {
        a4e = fmaf(RLO[m], A3[m], a4e);
        a4o = fmaf(RLO[m], A3[m + 2], a4o);
      }
      (lds + 3040)[j] = a4e;
      (lds + 3116)[j] = a4o;

      if (j >= 9) {
        float d3[4];
#pragma unroll
        for (int s = 0; s < 4; ++s) {
          float dd = 0.f;
#pragma unroll
          for (int t = 0; t < 4; ++t) {
            dd = fmaf(RHI[2 * t], e[6 + s + t], dd);
            dd = fmaf(RHI[2 * t + 1], o[6 + s + t], dd);
          }
          d3[s] = dd;
        }
        float* __restrict__ gD3 = out + OFF_D3 + (size_t)row * M3;
        const int gb = (p << 8) + 4 * (j - 9);
        if (gb + 1 < M3) {
          f2_t v01 = {d3[0], d3[1]};
          __builtin_nontemporal_store(v01, (f2u_t*)(gD3 + gb));
        }
        if (gb + 3 < M3) {
          f2_t v23 = {d3[2], d3[3]};
          __builtin_nontemporal_store(v23, (f2u_t*)(gD3 + gb + 2));
        }
        float d4e = 0.f, d4o = 0.f;
#pragma unroll
        for (int m = 0; m < 8; ++m) {
          d4e = fmaf(RHI[m], A3[m], d4e);
          d4o = fmaf(RHI[m], A3[m + 2], d4o);
        }
        float* __restrict__ gD4 = out + OFF_D4 + (size_t)row * M4;
        const int g4 = (p << 7) + 2 * (j - 9);
        if (g4 + 1 < M4) {
          f2_t v = {d4e, d4o};
          __builtin_nontemporal_store(v, (f2u_t*)(gD4 + g4));
        }
      }
    }
    __syncthreads();

    // ---- P3: lvl5+6 -> cD5, cD6, cA6 (16 pairs, b4=128p-18)
    if (tid < 16) {
      const int j = tid;
      const f4_t* E4 = (const f4_t*)(lds + 3040);
      const f4_t* O4 = (const f4_t*)(lds + 3116);
      f4_t ea = E4[j], eb = E4[j + 1], ec = E4[j + 2], ed = E4[j + 3];
      f4_t oa = O4[j], ob = O4[j + 1], oc = O4[j + 2], od = O4[j + 3];
      float e[13] = {ea.x, ea.y, ea.z, ea.w, eb.x, eb.y, eb.z,
                     eb.w, ec.x, ec.y, ec.z, ec.w, ed.x};
      float o[13] = {oa.x, oa.y, oa.z, oa.w, ob.x, ob.y, ob.z,
                     ob.w, oc.x, oc.y, oc.z, oc.w, od.x};
      float A5[10];
#pragma unroll
      for (int i = 0; i < 10; ++i) {
        float aa = 0.f;
#pragma unroll
        for (int t = 0; t < 4; ++t) {
          aa = fmaf(RLO[2 * t], e[i + t], aa);
          aa = fmaf(RLO[2 * t + 1], o[i + t], aa);
        }
        A5[i] = aa;
      }
      float d5[4];
#pragma unroll
      for (int s = 0; s < 4; ++s) {
        float dd = 0.f;
#pragma unroll
        for (int t = 0; t < 4; ++t) {
          dd = fmaf(RHI[2 * t], e[6 + s + t], dd);
          dd = fmaf(RHI[2 * t + 1], o[6 + s + t], dd);
        }
        d5[s] = dd;
      }
      float* __restrict__ gD5 = out + OFF_D5 + (size_t)row * M5;
      const int h5 = (p << 6) + 4 * j;
      if (h5 + 1 < M5) {
        f2_t v01 = {d5[0], d5[1]};
        __builtin_nontemporal_store(v01, (f2u_t*)(gD5 + h5));
      }
      if (h5 + 3 < M5) {
        f2_t v23 = {d5[2], d5[3]};
        __builtin_nontemporal_store(v23, (f2u_t*)(gD5 + h5 + 2));
      }
      float a6e = 0.f, a6o = 0.f, d6e = 0.f, d6o = 0.f;
#pragma unroll
      for (int m = 0; m < 8; ++m) {
        a6e = fmaf(RLO[m], A5[m], a6e);
        a6o = fmaf(RLO[m], A5[m + 2], a6o);
        d6e = fmaf(RHI[m], A5[m], d6e);
        d6o = fmaf(RHI[m], A5[m + 2], d6o);
      }
      const int g6 = (p << 5) + 2 * j;
      if (g6 + 1 < M6) {
        float* __restrict__ gA6 = out + OFF_A6 + (size_t)row * M6;
        float* __restrict__ gD6 = out + OFF_D6 + (size_t)row * M6;
        f2_t va = {a6e, a6o};
        f2_t vd = {d6e, d6o};
        __builtin_nontemporal_store(va, (f2u_t*)(gA6 + g6));
        __builtin_nontemporal_store(vd, (f2u_t*)(gD6 + g6));
      }
    }
  }
}

extern "C" void kernel_launch(void* const* d_in, const int* in_sizes, int n_in,
                              void* d_out, int out_size, void* d_ws,
                              size_t ws_size, hipStream_t stream) {
  const float* x = (const float*)d_in[0];
  float* out = (float*)d_out;
  // 257 role-A tiles (512 cD1 / 256 cD2 each) + 129 role-B tiles (32 cA6 each)
  dwt_all<<<dim3(386, 64), NT, 0, stream>>>(x, out);
}